// Round 1
// baseline (1656.679 us; speedup 1.0000x reference)
//
#include <hip/hip_runtime.h>

#define SHIFT 4

typedef short bf16x8 __attribute__((ext_vector_type(8)));
typedef float f32x4  __attribute__((ext_vector_type(4)));

#define MFMA(a, b, c) __builtin_amdgcn_mfma_f32_16x16x32_bf16((a), (b), (c), 0, 0, 0)

__device__ __forceinline__ unsigned short f2bf(float f) {
  unsigned int u = __float_as_uint(f);
  u += 0x7fffu + ((u >> 16) & 1u);   // round-to-nearest-even; inputs finite
  return (unsigned short)(u >> 16);
}
__device__ __forceinline__ float bf2f(unsigned short u) {
  return __uint_as_float(((unsigned int)u) << 16);
}

// ---------------------------------------------------------------------------
// Kernel 0: fp32 -> bf16 weight conversion
// ---------------------------------------------------------------------------
__global__ void k_cvt(const float* __restrict__ s, unsigned short* __restrict__ d, int n) {
  int i = blockIdx.x * blockDim.x + threadIdx.x;
  int st = gridDim.x * blockDim.x;
  for (; i < n; i += st) d[i] = f2bf(s[i]);
}

// ---------------------------------------------------------------------------
// Kernel 1: per-window  LN1 + shift-gather + QKV + attention + proj
// grid = 8192 (= 2 * 64 * 64 windows), block = 256 (4 waves; wave = M-tile)
// ---------------------------------------------------------------------------
__global__ __launch_bounds__(256) void k_attn(
    const float* __restrict__ x,
    const float* __restrict__ ln1g, const float* __restrict__ ln1b,
    const unsigned short* __restrict__ qkvw,   // bf16 [288][96]
    const float* __restrict__ qkvb,
    const float* __restrict__ lapA, const float* __restrict__ lapB,
    const unsigned short* __restrict__ projw,  // bf16 [96][96]
    const float* __restrict__ projb,
    unsigned short* __restrict__ attn_out)     // bf16 [8192*64][96], window layout
{
  __shared__ __align__(16) float xraw[64 * 97];
  __shared__ __align__(16) unsigned short Xb[64 * 104];
  __shared__ __align__(16) unsigned short Qs[64 * 104];
  __shared__ __align__(16) unsigned short Ks[64 * 104];
  __shared__ __align__(16) unsigned short Vt[96 * 72];   // V transposed [d][key]
  __shared__ __align__(16) float biasL[64 * 65];
  __shared__ __align__(16) unsigned short Pl[64 * 72];   // per-wave 16-row bands
  __shared__ __align__(16) unsigned short Ol[64 * 104];
  __shared__ float red1[256], red2[256];
  __shared__ float smu[64], srs[64];

  const int tid = threadIdx.x;
  const int wid = blockIdx.x;
  const int b   = wid >> 12;
  const int hi  = (wid >> 6) & 63;
  const int wi  = wid & 63;

  // Laplacian bias table (window-invariant)
  {
    const float a = lapA[0], bb = lapB[0];
    const float A2 = a * a;
    const float nh = -0.5f / (bb * bb);
    for (int idx = tid; idx < 4096; idx += 256) {
      int n = idx >> 6, m = idx & 63;
      int dd = abs((n >> 3) - (m >> 3)) + abs((n & 7) - (m & 7));
      biasL[n * 65 + m] = A2 * __expf(nh * (float)dd);
    }
  }
  // shifted gather: even band (hi even): src w = w-4 ; odd: w+4
  {
    const int sh = ((hi & 1) == 0) ? -SHIFT : SHIFT;
    for (int idx = tid; idx < 64 * 96; idx += 256) {
      int c = idx >> 6, t = idx & 63;
      int h = hi * 8 + (t >> 3);
      int w = ((wi * 8 + (t & 7)) + sh) & 511;
      xraw[t * 97 + c] = x[((b * 96 + c) << 18) + (h << 9) + w];
    }
  }
  __syncthreads();
  // LN1 stats (4 threads / token)
  {
    int t = tid >> 2, q = tid & 3;
    const float* r = &xraw[t * 97 + q * 24];
    float s1 = 0.f, s2 = 0.f;
#pragma unroll
    for (int i = 0; i < 24; ++i) { float v = r[i]; s1 += v; s2 += v * v; }
    red1[tid] = s1; red2[tid] = s2;
  }
  __syncthreads();
  if (tid < 64) {
    float s1 = red1[tid * 4] + red1[tid * 4 + 1] + red1[tid * 4 + 2] + red1[tid * 4 + 3];
    float s2 = red2[tid * 4] + red2[tid * 4 + 1] + red2[tid * 4 + 2] + red2[tid * 4 + 3];
    float mu = s1 * (1.f / 96.f);
    float var = s2 * (1.f / 96.f) - mu * mu;
    smu[tid] = mu; srs[tid] = rsqrtf(var + 1e-5f);
  }
  __syncthreads();
  for (int idx = tid; idx < 64 * 96; idx += 256) {
    int t = idx / 96, c = idx % 96;
    float v = (xraw[t * 97 + c] - smu[t]) * srs[t] * ln1g[c] + ln1b[c];
    Xb[t * 104 + c] = f2bf(v);
  }
  __syncthreads();

  const int lane = tid & 63;
  const int wv   = tid >> 6;
  const int l16  = lane & 15;
  const int lg   = lane >> 4;
  const int arow = wv * 16 + l16;
  const f32x4 zz = {0.f, 0.f, 0.f, 0.f};

  // ---- QKV GEMM: [64,96] @ [96,288]^T ----
  bf16x8 afr[3];
#pragma unroll
  for (int ks = 0; ks < 3; ++ks)
    afr[ks] = *reinterpret_cast<const bf16x8*>(&Xb[arow * 104 + ks * 32 + lg * 8]);

  const float qscale = 0.17677669529663687f;  // 32^-0.5
#pragma unroll 3
  for (int nt = 0; nt < 18; ++nt) {
    int col = nt * 16 + l16;
    f32x4 acc = zz;
#pragma unroll
    for (int ks = 0; ks < 3; ++ks) {
      bf16x8 bfr = *reinterpret_cast<const bf16x8*>(&qkvw[col * 96 + ks * 32 + lg * 8]);
      acc = MFMA(afr[ks], bfr, acc);
    }
    float bc = qkvb[col];
    int sec = col / 96;        // uniform per nt (96 = 6*16)
    int cc  = col - sec * 96;
#pragma unroll
    for (int j = 0; j < 4; ++j) {
      int row = wv * 16 + lg * 4 + j;
      float v = acc[j] + bc;
      if (sec == 0)      Qs[row * 104 + cc] = f2bf(v * qscale);
      else if (sec == 1) Ks[row * 104 + cc] = f2bf(v);
      else               Vt[cc * 72 + row]  = f2bf(v);
    }
  }
  __syncthreads();

  // ---- attention: each wave owns 16 query rows ----
  f32x4 oacc[6];
#pragma unroll
  for (int i = 0; i < 6; ++i) oacc[i] = zz;

#pragma unroll 1
  for (int h = 0; h < 3; ++h) {
    bf16x8 aq = *reinterpret_cast<const bf16x8*>(&Qs[arow * 104 + h * 32 + lg * 8]);
    f32x4 sc[4];
#pragma unroll
    for (int nt = 0; nt < 4; ++nt) {
      bf16x8 bk = *reinterpret_cast<const bf16x8*>(&Ks[(nt * 16 + l16) * 104 + h * 32 + lg * 8]);
      sc[nt] = MFMA(aq, bk, zz);
    }
    // softmax over 64 keys; row j lives in 16 lanes (l16) x 4 regs (nt)
#pragma unroll
    for (int j = 0; j < 4; ++j) {
      int qi = wv * 16 + lg * 4 + j;
      float v0 = sc[0][j] + biasL[qi * 65 +  0 + l16];
      float v1 = sc[1][j] + biasL[qi * 65 + 16 + l16];
      float v2 = sc[2][j] + biasL[qi * 65 + 32 + l16];
      float v3 = sc[3][j] + biasL[qi * 65 + 48 + l16];
      float mx = fmaxf(fmaxf(v0, v1), fmaxf(v2, v3));
#pragma unroll
      for (int off = 1; off < 16; off <<= 1) mx = fmaxf(mx, __shfl_xor(mx, off));
      float e0 = __expf(v0 - mx), e1 = __expf(v1 - mx);
      float e2 = __expf(v2 - mx), e3 = __expf(v3 - mx);
      float s = e0 + e1 + e2 + e3;
#pragma unroll
      for (int off = 1; off < 16; off <<= 1) s += __shfl_xor(s, off);
      float inv = 1.0f / s;
      Pl[qi * 72 +  0 + l16] = f2bf(e0 * inv);
      Pl[qi * 72 + 16 + l16] = f2bf(e1 * inv);
      Pl[qi * 72 + 32 + l16] = f2bf(e2 * inv);
      Pl[qi * 72 + 48 + l16] = f2bf(e3 * inv);
    }
    // PV (Pl band is wave-private; intra-wave LDS ordering suffices)
    bf16x8 ap0 = *reinterpret_cast<const bf16x8*>(&Pl[arow * 72 +  0 + lg * 8]);
    bf16x8 ap1 = *reinterpret_cast<const bf16x8*>(&Pl[arow * 72 + 32 + lg * 8]);
#pragma unroll
    for (int dt = 0; dt < 2; ++dt) {
      int vcol = h * 32 + dt * 16 + l16;
      bf16x8 bv0 = *reinterpret_cast<const bf16x8*>(&Vt[vcol * 72 +  0 + lg * 8]);
      bf16x8 bv1 = *reinterpret_cast<const bf16x8*>(&Vt[vcol * 72 + 32 + lg * 8]);
      oacc[h * 2 + dt] = MFMA(ap0, bv0, oacc[h * 2 + dt]);
      oacc[h * 2 + dt] = MFMA(ap1, bv1, oacc[h * 2 + dt]);
    }
  }
  // stash O for proj A-frags
#pragma unroll
  for (int i = 0; i < 6; ++i)
#pragma unroll
    for (int j = 0; j < 4; ++j) {
      int row = wv * 16 + lg * 4 + j;
      Ol[row * 104 + i * 16 + l16] = f2bf(oacc[i][j]);
    }
  __syncthreads();

  // ---- proj: [64,96] @ [96,96]^T ----
  bf16x8 ao[3];
#pragma unroll
  for (int ks = 0; ks < 3; ++ks)
    ao[ks] = *reinterpret_cast<const bf16x8*>(&Ol[arow * 104 + ks * 32 + lg * 8]);
#pragma unroll 2
  for (int nt = 0; nt < 6; ++nt) {
    int col = nt * 16 + l16;
    f32x4 acc = zz;
#pragma unroll
    for (int ks = 0; ks < 3; ++ks) {
      bf16x8 bfr = *reinterpret_cast<const bf16x8*>(&projw[col * 96 + ks * 32 + lg * 8]);
      acc = MFMA(ao[ks], bfr, acc);
    }
    float pb = projb[col];
#pragma unroll
    for (int j = 0; j < 4; ++j) {
      int row = wv * 16 + lg * 4 + j;
      attn_out[(wid * 64 + row) * 96 + col] = f2bf(acc[j] + pb);
    }
  }
}

// ---------------------------------------------------------------------------
// Kernel 2: per 64-pixel strip  gather(inv-shift)+residual + LN2 + MLP + out
// grid = 8192 (= 2 * 512 * 8), block = 256
// ---------------------------------------------------------------------------
__global__ __launch_bounds__(256) void k_mlp(
    const float* __restrict__ x,
    const unsigned short* __restrict__ attn_out,
    const float* __restrict__ ln2g, const float* __restrict__ ln2b,
    const unsigned short* __restrict__ w1,  // bf16 [384][96]
    const float* __restrict__ b1,
    const unsigned short* __restrict__ w2,  // bf16 [96][384]
    const float* __restrict__ b2,
    float* __restrict__ out)
{
  __shared__ __align__(16) float xt[64 * 97];
  __shared__ __align__(16) unsigned short Xb[64 * 104];
  __shared__ __align__(16) unsigned short Hl[64 * 392];
  __shared__ __align__(16) float obuf[96 * 65];
  __shared__ float red1[256], red2[256];
  __shared__ float smu[64], srs[64];

  const int tid = threadIdx.x;
  const int bid = blockIdx.x;
  const int b  = bid >> 12;
  const int h  = (bid >> 3) & 511;
  const int w0 = (bid & 7) << 6;

  // shortcut
  for (int idx = tid; idx < 6144; idx += 256) {
    int c = idx >> 6, p = idx & 63;
    xt[p * 97 + c] = x[((b * 96 + c) << 18) + (h << 9) + w0 + p];
  }
  __syncthreads();
  // + inverse-shift gather of window-attention output
  {
    const int sh = (((h >> 3) & 1) == 0) ? SHIFT : -SHIFT;
    for (int idx = tid; idx < 6144; idx += 256) {
      int p = idx / 96, c = idx % 96;
      int w2s = (w0 + p + sh) & 511;
      int win = (b << 12) + ((h >> 3) << 6) + (w2s >> 3);
      int tok = ((h & 7) << 3) + (w2s & 7);
      xt[p * 97 + c] += bf2f(attn_out[(win * 64 + tok) * 96 + c]);
    }
  }
  __syncthreads();
  // LN2
  {
    int t = tid >> 2, q = tid & 3;
    const float* r = &xt[t * 97 + q * 24];
    float s1 = 0.f, s2 = 0.f;
#pragma unroll
    for (int i = 0; i < 24; ++i) { float v = r[i]; s1 += v; s2 += v * v; }
    red1[tid] = s1; red2[tid] = s2;
  }
  __syncthreads();
  if (tid < 64) {
    float s1 = red1[tid * 4] + red1[tid * 4 + 1] + red1[tid * 4 + 2] + red1[tid * 4 + 3];
    float s2 = red2[tid * 4] + red2[tid * 4 + 1] + red2[tid * 4 + 2] + red2[tid * 4 + 3];
    float mu = s1 * (1.f / 96.f);
    float var = s2 * (1.f / 96.f) - mu * mu;
    smu[tid] = mu; srs[tid] = rsqrtf(var + 1e-5f);
  }
  __syncthreads();
  for (int idx = tid; idx < 6144; idx += 256) {
    int t = idx / 96, c = idx % 96;
    float v = (xt[t * 97 + c] - smu[t]) * srs[t] * ln2g[c] + ln2b[c];
    Xb[t * 104 + c] = f2bf(v);
  }
  __syncthreads();

  const int lane = tid & 63;
  const int wv   = tid >> 6;
  const int l16  = lane & 15;
  const int lg   = lane >> 4;
  const int arow = wv * 16 + l16;
  const f32x4 zz = {0.f, 0.f, 0.f, 0.f};

  // ---- GEMM1 + exact GELU: [64,96] @ [96,384]^T ----
  bf16x8 a1[3];
#pragma unroll
  for (int ks = 0; ks < 3; ++ks)
    a1[ks] = *reinterpret_cast<const bf16x8*>(&Xb[arow * 104 + ks * 32 + lg * 8]);
#pragma unroll 3
  for (int nt = 0; nt < 24; ++nt) {
    int col = nt * 16 + l16;
    f32x4 acc = zz;
#pragma unroll
    for (int ks = 0; ks < 3; ++ks) {
      bf16x8 bfr = *reinterpret_cast<const bf16x8*>(&w1[col * 96 + ks * 32 + lg * 8]);
      acc = MFMA(a1[ks], bfr, acc);
    }
    float bb = b1[col];
#pragma unroll
    for (int j = 0; j < 4; ++j) {
      int row = wv * 16 + lg * 4 + j;
      float v = acc[j] + bb;
      v = 0.5f * v * (1.f + erff(v * 0.70710678118654752f));
      Hl[row * 392 + col] = f2bf(v);
    }
  }
  __syncthreads();

  // ---- GEMM2 + residual: [64,384] @ [384,96]^T ----
  bf16x8 ah[12];
#pragma unroll
  for (int ks = 0; ks < 12; ++ks)
    ah[ks] = *reinterpret_cast<const bf16x8*>(&Hl[arow * 392 + ks * 32 + lg * 8]);
#pragma unroll 2
  for (int nt = 0; nt < 6; ++nt) {
    int col = nt * 16 + l16;
    f32x4 acc = zz;
#pragma unroll
    for (int ks = 0; ks < 12; ++ks) {
      bf16x8 bfr = *reinterpret_cast<const bf16x8*>(&w2[col * 384 + ks * 32 + lg * 8]);
      acc = MFMA(ah[ks], bfr, acc);
    }
    float bb = b2[col];
#pragma unroll
    for (int j = 0; j < 4; ++j) {
      int row = wv * 16 + lg * 4 + j;
      obuf[col * 65 + row] = acc[j] + bb + xt[row * 97 + col];
    }
  }
  __syncthreads();
  // coalesced planar store
  for (int idx = tid; idx < 6144; idx += 256) {
    int c = idx >> 6, t = idx & 63;
    out[((b * 96 + c) << 18) + (h << 9) + w0 + t] = obuf[c * 65 + t];
  }
}

// ---------------------------------------------------------------------------
extern "C" void kernel_launch(void* const* d_in, const int* in_sizes, int n_in,
                              void* d_out, int out_size, void* d_ws, size_t ws_size,
                              hipStream_t stream) {
  const float* x     = (const float*)d_in[0];
  const float* ln1g  = (const float*)d_in[1];
  const float* ln1b  = (const float*)d_in[2];
  const float* qkv_w = (const float*)d_in[3];
  const float* qkv_b = (const float*)d_in[4];
  const float* lapA  = (const float*)d_in[5];
  const float* lapB  = (const float*)d_in[6];
  const float* prj_w = (const float*)d_in[7];
  const float* prj_b = (const float*)d_in[8];
  const float* ln2g  = (const float*)d_in[9];
  const float* ln2b  = (const float*)d_in[10];
  const float* w1f   = (const float*)d_in[11];
  const float* b1    = (const float*)d_in[12];
  const float* w2f   = (const float*)d_in[13];
  const float* b2    = (const float*)d_in[14];

  char* ws = (char*)d_ws;
  // ws layout (bytes):
  //   [0, 100663296)            attn_out bf16 [524288][96]
  //   +55296 / +18432 / +73728 / +73728 : qkv_wb / proj_wb / w1b / w2b
  unsigned short* attn  = (unsigned short*)ws;
  unsigned short* qkvwb = (unsigned short*)(ws + 100663296);
  unsigned short* prjwb = (unsigned short*)(ws + 100718592);
  unsigned short* w1b   = (unsigned short*)(ws + 100737024);
  unsigned short* w2b   = (unsigned short*)(ws + 100810752);

  k_cvt<<<64, 256, 0, stream>>>(qkv_w, qkvwb, 288 * 96);
  k_cvt<<<64, 256, 0, stream>>>(prj_w, prjwb, 96 * 96);
  k_cvt<<<64, 256, 0, stream>>>(w1f,   w1b,   384 * 96);
  k_cvt<<<64, 256, 0, stream>>>(w2f,   w2b,   96 * 384);

  k_attn<<<8192, 256, 0, stream>>>(x, ln1g, ln1b, qkvwb, qkv_b, lapA, lapB,
                                   prjwb, prj_b, attn);
  k_mlp<<<8192, 256, 0, stream>>>(x, attn, ln2g, ln2b, w1b, b1, w2b, b2,
                                  (float*)d_out);
}

// Round 2
// 817.169 us; speedup vs baseline: 2.0273x; 2.0273x over previous
//
#include <hip/hip_runtime.h>

#define SHIFT 4

typedef short bf16x8 __attribute__((ext_vector_type(8)));
typedef float f32x4  __attribute__((ext_vector_type(4)));

#define MFMA(a, b, c) __builtin_amdgcn_mfma_f32_16x16x32_bf16((a), (b), (c), 0, 0, 0)

__device__ __forceinline__ unsigned short f2bf(float f) {
  unsigned int u = __float_as_uint(f);
  u += 0x7fffu + ((u >> 16) & 1u);   // round-to-nearest-even; inputs finite
  return (unsigned short)(u >> 16);
}
__device__ __forceinline__ float bf2f(unsigned short u) {
  return __uint_as_float(((unsigned int)u) << 16);
}

// ---------------------------------------------------------------------------
// Kernel 0: fp32 -> bf16 weight conversion
// ---------------------------------------------------------------------------
__global__ void k_cvt(const float* __restrict__ s, unsigned short* __restrict__ d, int n) {
  int i = blockIdx.x * blockDim.x + threadIdx.x;
  int st = gridDim.x * blockDim.x;
  for (; i < n; i += st) d[i] = f2bf(s[i]);
}

// ---------------------------------------------------------------------------
// Kernel 1: per-window  LN1 + shift-gather + QKV + attention + proj
// grid = 8192, block = 256 (4 waves; wave = 16-row M-tile)
// LDS ~55 KB -> 2 blocks/CU
// ---------------------------------------------------------------------------
__global__ __launch_bounds__(256, 2) void k_attn(
    const float* __restrict__ x,
    const float* __restrict__ ln1g, const float* __restrict__ ln1b,
    const unsigned short* __restrict__ qkvw,   // bf16 [288][96]
    const float* __restrict__ qkvb,
    const float* __restrict__ lapA, const float* __restrict__ lapB,
    const unsigned short* __restrict__ projw,  // bf16 [96][96]
    const float* __restrict__ projb,
    unsigned short* __restrict__ attn_out)     // bf16 [8192*64][96], window layout
{
  // R1: Xb (stride 104) -> Pl (stride 72, wave-band-private)
  __shared__ __align__(16) unsigned short R1[64 * 104];
  __shared__ __align__(16) unsigned short Qs[64 * 104];  // later reused as Ol
  __shared__ __align__(16) unsigned short Ks[64 * 104];
  __shared__ __align__(16) unsigned short Vt[96 * 72];   // V transposed [d][key]
  __shared__ float red1[256], red2[256];
  __shared__ float smu[64], srs[64];

  const int tid = threadIdx.x;
  const int wid = blockIdx.x;
  const int b   = wid >> 12;
  const int hi  = (wid >> 6) & 63;
  const int wi  = wid & 63;
  const int lane = tid & 63;
  const int wv   = tid >> 6;
  const int tok  = lane;                 // owner token for LN phase

  // ---- shifted gather into registers: thread owns (tok, c = wv + 4k) ----
  float xreg[24];
  {
    const int sh = ((hi & 1) == 0) ? -SHIFT : SHIFT;
    const int h = hi * 8 + (tok >> 3);
    const int w = ((wi * 8 + (tok & 7)) + sh) & 511;
    const float* xp = x + (h << 9) + w;
#pragma unroll
    for (int k2 = 0; k2 < 24; ++k2) {
      int c = wv + 4 * k2;
      xreg[k2] = xp[(b * 96 + c) << 18];
    }
  }
  // ---- LN1 stats ----
  {
    float s1 = 0.f, s2 = 0.f;
#pragma unroll
    for (int k2 = 0; k2 < 24; ++k2) { float v = xreg[k2]; s1 += v; s2 += v * v; }
    red1[tid] = s1; red2[tid] = s2;
  }
  __syncthreads();
  if (tid < 64) {
    float s1 = red1[tid] + red1[tid + 64] + red1[tid + 128] + red1[tid + 192];
    float s2 = red2[tid] + red2[tid + 64] + red2[tid + 128] + red2[tid + 192];
    float mu = s1 * (1.f / 96.f);
    float var = s2 * (1.f / 96.f) - mu * mu;
    smu[tid] = mu; srs[tid] = rsqrtf(var + 1e-5f);
  }
  __syncthreads();
  {
    float mu = smu[tok], rs = srs[tok];
#pragma unroll
    for (int k2 = 0; k2 < 24; ++k2) {
      int c = wv + 4 * k2;
      R1[tok * 104 + c] = f2bf((xreg[k2] - mu) * rs * ln1g[c] + ln1b[c]);
    }
  }
  __syncthreads();

  const int l16  = lane & 15;
  const int lg   = lane >> 4;
  const int arow = wv * 16 + l16;
  const f32x4 zz = {0.f, 0.f, 0.f, 0.f};

  // ---- QKV GEMM: [64,96] @ [96,288]^T ----
  bf16x8 afr[3];
#pragma unroll
  for (int ks = 0; ks < 3; ++ks)
    afr[ks] = *reinterpret_cast<const bf16x8*>(&R1[arow * 104 + ks * 32 + lg * 8]);

  const float qscale = 0.17677669529663687f;  // 32^-0.5
#pragma unroll 3
  for (int nt = 0; nt < 18; ++nt) {
    int col = nt * 16 + l16;
    f32x4 acc = zz;
#pragma unroll
    for (int ks = 0; ks < 3; ++ks) {
      bf16x8 bfr = *reinterpret_cast<const bf16x8*>(&qkvw[col * 96 + ks * 32 + lg * 8]);
      acc = MFMA(afr[ks], bfr, acc);
    }
    float bc = qkvb[col];
    int sec = col / 96;        // uniform per nt (96 = 6*16)
    int cc  = col - sec * 96;
#pragma unroll
    for (int j = 0; j < 4; ++j) {
      int row = wv * 16 + lg * 4 + j;
      float v = acc[j] + bc;
      if (sec == 0)      Qs[row * 104 + cc] = f2bf(v * qscale);
      else if (sec == 1) Ks[row * 104 + cc] = f2bf(v);
      else               Vt[cc * 72 + row]  = f2bf(v);
    }
  }
  __syncthreads();

  // ---- Laplacian bias in registers (15 distinct values, computed per lane) ----
  float bias_r[4][4];
  {
    const float a = lapA[0], bb = lapB[0];
    const float A2 = a * a;
    const float nh = -0.5f / (bb * bb);
#pragma unroll
    for (int j = 0; j < 4; ++j) {
      int qi = wv * 16 + lg * 4 + j;
      int qr = qi >> 3, qc = qi & 7;
#pragma unroll
      for (int nt = 0; nt < 4; ++nt) {
        int key = nt * 16 + l16;
        int dd = abs(qr - (key >> 3)) + abs(qc - (key & 7));
        bias_r[j][nt] = A2 * __expf(nh * (float)dd);
      }
    }
  }

  // ---- attention: each wave owns 16 query rows; Pl lives in R1 (stride 72) ----
  f32x4 oacc[6];
#pragma unroll
  for (int i = 0; i < 6; ++i) oacc[i] = zz;

#pragma unroll 1
  for (int h = 0; h < 3; ++h) {
    bf16x8 aq = *reinterpret_cast<const bf16x8*>(&Qs[arow * 104 + h * 32 + lg * 8]);
    f32x4 sc[4];
#pragma unroll
    for (int nt = 0; nt < 4; ++nt) {
      bf16x8 bk = *reinterpret_cast<const bf16x8*>(&Ks[(nt * 16 + l16) * 104 + h * 32 + lg * 8]);
      sc[nt] = MFMA(aq, bk, zz);
    }
#pragma unroll
    for (int j = 0; j < 4; ++j) {
      int qi = wv * 16 + lg * 4 + j;
      float v0 = sc[0][j] + bias_r[j][0];
      float v1 = sc[1][j] + bias_r[j][1];
      float v2 = sc[2][j] + bias_r[j][2];
      float v3 = sc[3][j] + bias_r[j][3];
      float mx = fmaxf(fmaxf(v0, v1), fmaxf(v2, v3));
#pragma unroll
      for (int off = 1; off < 16; off <<= 1) mx = fmaxf(mx, __shfl_xor(mx, off));
      float e0 = __expf(v0 - mx), e1 = __expf(v1 - mx);
      float e2 = __expf(v2 - mx), e3 = __expf(v3 - mx);
      float s = e0 + e1 + e2 + e3;
#pragma unroll
      for (int off = 1; off < 16; off <<= 1) s += __shfl_xor(s, off);
      float inv = 1.0f / s;
      R1[qi * 72 +  0 + l16] = f2bf(e0 * inv);
      R1[qi * 72 + 16 + l16] = f2bf(e1 * inv);
      R1[qi * 72 + 32 + l16] = f2bf(e2 * inv);
      R1[qi * 72 + 48 + l16] = f2bf(e3 * inv);
    }
    // PV (Pl band is wave-private; intra-wave LDS ordering suffices)
    bf16x8 ap0 = *reinterpret_cast<const bf16x8*>(&R1[arow * 72 +  0 + lg * 8]);
    bf16x8 ap1 = *reinterpret_cast<const bf16x8*>(&R1[arow * 72 + 32 + lg * 8]);
#pragma unroll
    for (int dt = 0; dt < 2; ++dt) {
      int vcol = h * 32 + dt * 16 + l16;
      bf16x8 bv0 = *reinterpret_cast<const bf16x8*>(&Vt[vcol * 72 +  0 + lg * 8]);
      bf16x8 bv1 = *reinterpret_cast<const bf16x8*>(&Vt[vcol * 72 + 32 + lg * 8]);
      oacc[h * 2 + dt] = MFMA(ap0, bv0, oacc[h * 2 + dt]);
      oacc[h * 2 + dt] = MFMA(ap1, bv1, oacc[h * 2 + dt]);
    }
  }
  // stash O into Qs region (wave-band-private: safe without a block sync)
  unsigned short* Ol = Qs;
#pragma unroll
  for (int i = 0; i < 6; ++i)
#pragma unroll
    for (int j = 0; j < 4; ++j) {
      int row = wv * 16 + lg * 4 + j;
      Ol[row * 104 + i * 16 + l16] = f2bf(oacc[i][j]);
    }

  // ---- proj: [64,96] @ [96,96]^T ----
  bf16x8 ao[3];
#pragma unroll
  for (int ks = 0; ks < 3; ++ks)
    ao[ks] = *reinterpret_cast<const bf16x8*>(&Ol[arow * 104 + ks * 32 + lg * 8]);
#pragma unroll 2
  for (int nt = 0; nt < 6; ++nt) {
    int col = nt * 16 + l16;
    f32x4 acc = zz;
#pragma unroll
    for (int ks = 0; ks < 3; ++ks) {
      bf16x8 bfr = *reinterpret_cast<const bf16x8*>(&projw[col * 96 + ks * 32 + lg * 8]);
      acc = MFMA(ao[ks], bfr, acc);
    }
    float pb = projb[col];
#pragma unroll
    for (int j = 0; j < 4; ++j) {
      int row = wv * 16 + lg * 4 + j;
      attn_out[(wid * 64 + row) * 96 + col] = f2bf(acc[j] + pb);
    }
  }
}

// ---------------------------------------------------------------------------
// Kernel 2: per 64-pixel strip  gather(inv-shift)+residual + LN2 + MLP + out
// grid = 8192, block = 256.  LDS ~33 KB, VGPR<=128 -> 4 blocks/CU target
// ---------------------------------------------------------------------------
__global__ __launch_bounds__(256, 4) void k_mlp(
    const float* __restrict__ x,
    const unsigned short* __restrict__ attn_out,
    const float* __restrict__ ln2g, const float* __restrict__ ln2b,
    const unsigned short* __restrict__ w1,  // bf16 [384][96]
    const float* __restrict__ b1,
    const unsigned short* __restrict__ w2,  // bf16 [96][384]
    const float* __restrict__ b2,
    float* __restrict__ out)
{
  // big: [0,6656) Xb (stride 104) | [6656,15360) Hl chunk (stride 136) / xadd (stride 104)
  // obuf (float, stride 65, 24960 B) aliases the whole thing in the epilogue.
  __shared__ __align__(16) unsigned short big[15360];
  __shared__ float red1[256], red2[256];
  __shared__ float smu[64], srs[64];

  unsigned short* Xb   = big;
  unsigned short* Hl   = big + 6656;
  unsigned short* xadd = big + 6656;
  float*          obuf = reinterpret_cast<float*>(big);

  const int tid = threadIdx.x;
  const int bid = blockIdx.x;
  const int b  = bid >> 12;
  const int h  = (bid >> 3) & 511;
  const int w0 = (bid & 7) << 6;
  const int lane = tid & 63;
  const int wv   = tid >> 6;
  const int tok  = lane;

  // ---- inverse-shift gather of attention output (vectorized 16B) ----
  {
    const int shm = (((h >> 3) & 1) == 0) ? SHIFT : -SHIFT;
#pragma unroll
    for (int v = 0; v < 3; ++v) {
      int idx = tid + v * 256;           // 0..767
      int p  = idx / 12;                 // pixel 0..63
      int c8 = (idx - p * 12) * 8;       // channel块 0,8,...,88
      int w2s = (w0 + p + shm) & 511;
      int win = (b << 12) + ((h >> 3) << 6) + (w2s >> 3);
      int tk  = ((h & 7) << 3) + (w2s & 7);
      *reinterpret_cast<bf16x8*>(&xadd[p * 104 + c8]) =
          *reinterpret_cast<const bf16x8*>(&attn_out[(win * 64 + tk) * 96 + c8]);
    }
  }
  // ---- shortcut x into registers: thread owns (tok, c = wv + 4k) ----
  float xreg[24];
  {
    const float* xp = x + (h << 9) + w0 + tok;
#pragma unroll
    for (int k2 = 0; k2 < 24; ++k2) {
      int c = wv + 4 * k2;
      xreg[k2] = xp[(b * 96 + c) << 18];
    }
  }
  __syncthreads();
#pragma unroll
  for (int k2 = 0; k2 < 24; ++k2) {
    int c = wv + 4 * k2;
    xreg[k2] += bf2f(xadd[tok * 104 + c]);   // xreg = residual tokens
  }
  // ---- LN2 stats ----
  {
    float s1 = 0.f, s2 = 0.f;
#pragma unroll
    for (int k2 = 0; k2 < 24; ++k2) { float v = xreg[k2]; s1 += v; s2 += v * v; }
    red1[tid] = s1; red2[tid] = s2;
  }
  __syncthreads();
  if (tid < 64) {
    float s1 = red1[tid] + red1[tid + 64] + red1[tid + 128] + red1[tid + 192];
    float s2 = red2[tid] + red2[tid + 64] + red2[tid + 128] + red2[tid + 192];
    float mu = s1 * (1.f / 96.f);
    float var = s2 * (1.f / 96.f) - mu * mu;
    smu[tid] = mu; srs[tid] = rsqrtf(var + 1e-5f);
  }
  __syncthreads();
  {
    float mu = smu[tok], rs = srs[tok];
#pragma unroll
    for (int k2 = 0; k2 < 24; ++k2) {
      int c = wv + 4 * k2;
      Xb[tok * 104 + c] = f2bf((xreg[k2] - mu) * rs * ln2g[c] + ln2b[c]);
    }
  }
  __syncthreads();

  const int l16  = lane & 15;
  const int lg   = lane >> 4;
  const int arow = wv * 16 + l16;
  const f32x4 zz = {0.f, 0.f, 0.f, 0.f};

  bf16x8 a1[3];
#pragma unroll
  for (int ks = 0; ks < 3; ++ks)
    a1[ks] = *reinterpret_cast<const bf16x8*>(&Xb[arow * 104 + ks * 32 + lg * 8]);

  f32x4 acc2[6];
#pragma unroll
  for (int i = 0; i < 6; ++i) acc2[i] = zz;

  // ---- hidden dim in 3 chunks of 128: GEMM1+GELU -> Hl chunk -> GEMM2 accum ----
  // Hl is wave-band-private (each wave writes/reads only rows [wv*16, wv*16+16)),
  // so no __syncthreads inside the chunk loop.
#pragma unroll 1
  for (int ch = 0; ch < 3; ++ch) {
#pragma unroll 2
    for (int nt = 0; nt < 8; ++nt) {
      int col = ch * 128 + nt * 16 + l16;
      f32x4 acc = zz;
#pragma unroll
      for (int ks = 0; ks < 3; ++ks) {
        bf16x8 bfr = *reinterpret_cast<const bf16x8*>(&w1[col * 96 + ks * 32 + lg * 8]);
        acc = MFMA(a1[ks], bfr, acc);
      }
      float bb = b1[col];
#pragma unroll
      for (int j = 0; j < 4; ++j) {
        int row = wv * 16 + lg * 4 + j;
        float v = acc[j] + bb;
        // gelu(v) = v * sigmoid(1.5957691 v + 0.071354816 v^3)  (tanh form)
        float t = v * fmaf(0.071354816f, v * v, 1.5957691f);
        float g = v * __builtin_amdgcn_rcpf(1.f + __expf(-t));
        Hl[row * 136 + nt * 16 + l16] = f2bf(g);
      }
    }
    bf16x8 ah[4];
#pragma unroll
    for (int ks = 0; ks < 4; ++ks)
      ah[ks] = *reinterpret_cast<const bf16x8*>(&Hl[arow * 136 + ks * 32 + lg * 8]);
#pragma unroll
    for (int nt = 0; nt < 6; ++nt) {
      int col = nt * 16 + l16;
#pragma unroll
      for (int ks = 0; ks < 4; ++ks) {
        bf16x8 bfr = *reinterpret_cast<const bf16x8*>(&w2[col * 384 + ch * 128 + ks * 32 + lg * 8]);
        acc2[nt] = MFMA(ah[ks], bfr, acc2[nt]);
      }
    }
  }
  __syncthreads();   // all waves done reading their Hl bands before obuf tramples
#pragma unroll
  for (int nt = 0; nt < 6; ++nt) {
    int col = nt * 16 + l16;
    float bb = b2[col];
#pragma unroll
    for (int j = 0; j < 4; ++j) {
      int row = wv * 16 + lg * 4 + j;
      obuf[col * 65 + row] = acc2[nt][j] + bb;
    }
  }
  __syncthreads();
  // ---- coalesced planar store + residual from registers ----
#pragma unroll
  for (int k2 = 0; k2 < 24; ++k2) {
    int c = wv + 4 * k2;
    out[((b * 96 + c) << 18) + (h << 9) + w0 + tok] = obuf[c * 65 + tok] + xreg[k2];
  }
}

// ---------------------------------------------------------------------------
extern "C" void kernel_launch(void* const* d_in, const int* in_sizes, int n_in,
                              void* d_out, int out_size, void* d_ws, size_t ws_size,
                              hipStream_t stream) {
  const float* x     = (const float*)d_in[0];
  const float* ln1g  = (const float*)d_in[1];
  const float* ln1b  = (const float*)d_in[2];
  const float* qkv_w = (const float*)d_in[3];
  const float* qkv_b = (const float*)d_in[4];
  const float* lapA  = (const float*)d_in[5];
  const float* lapB  = (const float*)d_in[6];
  const float* prj_w = (const float*)d_in[7];
  const float* prj_b = (const float*)d_in[8];
  const float* ln2g  = (const float*)d_in[9];
  const float* ln2b  = (const float*)d_in[10];
  const float* w1f   = (const float*)d_in[11];
  const float* b1    = (const float*)d_in[12];
  const float* w2f   = (const float*)d_in[13];
  const float* b2    = (const float*)d_in[14];

  char* ws = (char*)d_ws;
  unsigned short* attn  = (unsigned short*)ws;
  unsigned short* qkvwb = (unsigned short*)(ws + 100663296);
  unsigned short* prjwb = (unsigned short*)(ws + 100718592);
  unsigned short* w1b   = (unsigned short*)(ws + 100737024);
  unsigned short* w2b   = (unsigned short*)(ws + 100810752);

  k_cvt<<<64, 256, 0, stream>>>(qkv_w, qkvwb, 288 * 96);
  k_cvt<<<64, 256, 0, stream>>>(prj_w, prjwb, 96 * 96);
  k_cvt<<<64, 256, 0, stream>>>(w1f,   w1b,   384 * 96);
  k_cvt<<<64, 256, 0, stream>>>(w2f,   w2b,   96 * 384);

  k_attn<<<8192, 256, 0, stream>>>(x, ln1g, ln1b, qkvwb, qkv_b, lapA, lapB,
                                   prjwb, prj_b, attn);
  k_mlp<<<8192, 256, 0, stream>>>(x, attn, ln2g, ln2b, w1b, b1, w2b, b2,
                                  (float*)d_out);
}